// Round 6
// baseline (349.293 us; speedup 1.0000x reference)
//
#include <hip/hip_runtime.h>
#include <math.h>

// Problem: B=16, D=256, H=32, W=32 -> N=16384 tokens; K=4096 codes.
#define DD    256
#define HWD   1024
#define NTOK  16384
#define KK    4096

typedef __attribute__((ext_vector_type(8))) short     bf16x8;
typedef __attribute__((ext_vector_type(4))) float     f32x4;
typedef __attribute__((ext_vector_type(8))) unsigned short ushort8;

// ---- bf16 helpers (RNE, bit-level) ----------------------------------------
__device__ __forceinline__ unsigned short f2bf(float f) {
    unsigned u = __float_as_uint(f);
    unsigned r = (u + 0x7FFFu + ((u >> 16) & 1u)) >> 16;
    return (unsigned short)r;
}
__device__ __forceinline__ float bf2f(unsigned short h) {
    return __uint_as_float(((unsigned)h) << 16);
}

#define GLOAD16(gaddr, laddr)                                                   \
    __builtin_amdgcn_global_load_lds(                                           \
        (const __attribute__((address_space(1))) unsigned int*)(gaddr),         \
        (__attribute__((address_space(3))) unsigned int*)(laddr), 16, 0, 0)

// ===========================================================================
// Prep A: x [16,256,1024] f32 -> Ax [16384][768] bf16 triplets (hx, lx, hx)
// ===========================================================================
__global__ __launch_bounds__(256) void vq_splitx(const float* __restrict__ x,
                                                 unsigned short* __restrict__ Ax) {
    const int blk = blockIdx.x;               // 256 blocks
    const int tid = threadIdx.x;
    const int b = blk >> 4;
    const int hw0 = (blk & 15) << 6;

    __shared__ float xls[DD * 64];            // [d][i] 64 KB

    const float* xb = x + (size_t)b * (DD * HWD) + hw0;
    #pragma unroll 8
    for (int it = 0; it < 64; ++it) {
        int e = it * 256 + tid;
        int d = e >> 6, i = e & 63;
        xls[d * 64 + i] = xb[d * HWD + i];
    }
    __syncthreads();

    const int tok_l = tid >> 2;               // 0..63
    const int part  = tid & 3;                // d-range part*64..+64
    const int n = b * HWD + hw0 + tok_l;
    unsigned short* dst = Ax + (size_t)n * 768 + part * 192;

    #pragma unroll
    for (int c8 = 0; c8 < 8; ++c8) {
        const int dbase = part * 64 + c8 * 8;
        ushort8 w0, w1, w2;
        #pragma unroll
        for (int q = 0; q < 8; ++q) {
            float v = xls[(dbase + q) * 64 + tok_l];
            unsigned short hq = f2bf(v);
            unsigned short lq = f2bf(v - bf2f(hq));
            const int i0 = 3 * q, i1 = 3 * q + 1, i2 = 3 * q + 2;
            if (i0 < 8) w0[i0] = hq; else if (i0 < 16) w1[i0 - 8] = hq; else w2[i0 - 16] = hq;
            if (i1 < 8) w0[i1] = lq; else if (i1 < 16) w1[i1 - 8] = lq; else w2[i1 - 16] = lq;
            if (i2 < 8) w0[i2] = hq; else if (i2 < 16) w1[i2 - 8] = hq; else w2[i2 - 16] = hq;
        }
        *(ushort8*)(dst + c8 * 24)      = w0;
        *(ushort8*)(dst + c8 * 24 + 8)  = w1;
        *(ushort8*)(dst + c8 * 24 + 16) = w2;
    }
}

// ===========================================================================
// Prep B: cb [4096][256] f32 -> Bc [4096][768] bf16 triplets (hc, hc, lc)
// ===========================================================================
__global__ __launch_bounds__(256) void vq_splitc(const float* __restrict__ cb,
                                                 unsigned short* __restrict__ Bc) {
    const int gid = blockIdx.x * 256 + threadIdx.x;   // 512 blocks
    const int k = gid >> 5;
    const int j = gid & 31;                           // 8 d's per thread
    const float4* cb4 = (const float4*)cb;
    float4 a = cb4[k * 64 + j * 2];
    float4 bq = cb4[k * 64 + j * 2 + 1];
    float vv[8] = {a.x, a.y, a.z, a.w, bq.x, bq.y, bq.z, bq.w};
    ushort8 w0, w1, w2;
    #pragma unroll
    for (int q = 0; q < 8; ++q) {
        unsigned short hq = f2bf(vv[q]);
        unsigned short lq = f2bf(vv[q] - bf2f(hq));
        const int i0 = 3 * q, i1 = 3 * q + 1, i2 = 3 * q + 2;
        if (i0 < 8) w0[i0] = hq; else if (i0 < 16) w1[i0 - 8] = hq; else w2[i0 - 16] = hq;
        if (i1 < 8) w0[i1] = hq; else if (i1 < 16) w1[i1 - 8] = hq; else w2[i1 - 16] = hq;
        if (i2 < 8) w0[i2] = lq; else if (i2 < 16) w1[i2 - 8] = lq; else w2[i2 - 16] = lq;
    }
    unsigned short* dst = Bc + (size_t)k * 768 + j * 24;
    *(ushort8*)(dst)      = w0;
    *(ushort8*)(dst + 8)  = w1;
    *(ushort8*)(dst + 16) = w2;
}

// ===========================================================================
// cbT [256][4096] transpose
// ===========================================================================
__global__ __launch_bounds__(256) void vq_transpose(const float* __restrict__ cb,
                                                    float* __restrict__ cbT) {
    __shared__ float t[32][33];
    const int kt = blockIdx.x * 32, dt = blockIdx.y * 32;
    const int tx = threadIdx.x & 31, ty = threadIdx.x >> 5;
    #pragma unroll
    for (int r = 0; r < 32; r += 8)
        t[ty + r][tx] = cb[(kt + ty + r) * DD + dt + tx];
    __syncthreads();
    #pragma unroll
    for (int r = 0; r < 32; r += 8)
        cbT[(size_t)(dt + ty + r) * KK + kt + tx] = t[tx][ty + r];
}

// ===========================================================================
// cnorm: exact fp32 row norms of cb
// ===========================================================================
__global__ __launch_bounds__(256) void vq_cnorm(const float* __restrict__ cb,
                                                float* __restrict__ cnorm) {
    int k = (blockIdx.x * 256 + threadIdx.x) >> 6;
    int lane = threadIdx.x & 63;
    float4 v = reinterpret_cast<const float4*>(cb)[k * 64 + lane];
    float s = v.x * v.x + v.y * v.y + v.z * v.z + v.w * v.w;
    #pragma unroll
    for (int off = 32; off > 0; off >>= 1) s += __shfl_xor(s, off, 64);
    if (lane == 0) cnorm[k] = s;
}

__global__ void vq_zero(int* cnt) { if (threadIdx.x == 0) *cnt = 0; }

// ===========================================================================
// MFMA GEMM + fused running (best, second, argmin) — round-6 structure:
//  - tile 64(M) x 128(N), 4 waves (2x2), wave tile 32x64, NPH=8 -> grid 2048
//  - A frags loaded global->VGPR (L2-hot, no LDS, no redundancy w/ barrier)
//  - B staged to LDS via gload_lds with PRE-SWIZZLED source (col16 ^= row&7),
//    ds_read applies the same XOR -> bank-conflict-free (both-sides rule)
//  - double-buffered B, ONE __syncthreads per K-step (stage t+1 before
//    compute t -> staging latency hidden under MFMA), setprio around MFMA
// ===========================================================================
#define BN 128
#define BK 64
#define KRED 768
#define NPH 8
#define MARGIN 0.05f

__device__ __forceinline__ void stage_b(const unsigned short* __restrict__ Bc,
                                        unsigned short* BsFlat, int buf,
                                        int phase, int nt, int kk,
                                        int wid, int lane) {
    const int L3 = lane >> 3;                       // 0..7  (dest row offset)
    const int gcol16 = (lane & 7) ^ L3;             // pre-swizzled source col
    #pragma unroll
    for (int ib = 0; ib < 4; ++ib) {
        const int rb = wid * 32 + ib * 8;           // wave-uniform row base
        const int ldsoff = __builtin_amdgcn_readfirstlane((buf << 13) + rb * 64);
        const int code = phase * 512 + nt * 128 + rb + L3;
        GLOAD16(Bc + (size_t)code * KRED + kk * 64 + gcol16 * 8, BsFlat + ldsoff);
    }
}

__global__ __launch_bounds__(256, 4) void vq_gemm_min(
    const unsigned short* __restrict__ Ax,
    const unsigned short* __restrict__ Bc,
    const float* __restrict__ cnorm,
    float* __restrict__ candb, float* __restrict__ cands, int* __restrict__ candk)
{
    const int tid  = threadIdx.x;
    const int wid  = tid >> 6, lane = tid & 63;
    const int wm   = wid >> 1, wn = wid & 1;
    const int l15  = lane & 15, l4 = lane >> 4;     // l4 in 0..3
    const int mblk = blockIdx.x;       // 0..255 (64 tokens each)
    const int phase = blockIdx.y;      // 0..7  (512 codes each)

    __shared__ alignas(16) unsigned short Bs[2 * BN * BK];  // 32 KB dbuf
    __shared__ float mrg[64][2][3];

    float runb[8], runs[8];
    int   runk[8];
    #pragma unroll
    for (int e = 0; e < 8; ++e) { runb[e] = 3.0e38f; runs[e] = 3.0e38f; runk[e] = 0; }

    const unsigned short* Aw =
        Ax + (size_t)(mblk * 64 + wm * 32 + l15) * KRED + l4 * 8;

    f32x4 acc[2][4];
    #pragma unroll
    for (int mi = 0; mi < 2; ++mi)
        #pragma unroll
        for (int ni = 0; ni < 4; ++ni)
            acc[mi][ni] = (f32x4){0.f, 0.f, 0.f, 0.f};

    stage_b(Bc, Bs, 0, phase, 0, 0, wid, lane);
    __syncthreads();

    int cur = 0;
    for (int t = 0; t < 48; ++t) {                  // 4 nt-tiles x 12 K-steps
        const int nt = t / 12, kk = t - nt * 12;
        if (t < 47) {
            const int t1 = t + 1;
            const int nt1 = t1 / 12, kk1 = t1 - nt1 * 12;
            stage_b(Bc, Bs, cur ^ 1, phase, nt1, kk1, wid, lane);
        }
        __builtin_amdgcn_s_setprio(1);
        #pragma unroll
        for (int kh = 0; kh < 2; ++kh) {
            bf16x8 af[2], bfr[4];
            #pragma unroll
            for (int mi = 0; mi < 2; ++mi)
                af[mi] = *(const bf16x8*)(Aw + (size_t)mi * 16 * KRED + kk * 64 + kh * 32);
            #pragma unroll
            for (int ni = 0; ni < 4; ++ni) {
                const int r = wn * 64 + ni * 16 + l15;
                const int c16p = ((kh * 4 + l4) ^ (l15 & 7)) * 8;   // read-side XOR
                bfr[ni] = *(const bf16x8*)&Bs[(cur << 13) + r * 64 + c16p];
            }
            #pragma unroll
            for (int mi = 0; mi < 2; ++mi)
                #pragma unroll
                for (int ni = 0; ni < 4; ++ni)
                    acc[mi][ni] = __builtin_amdgcn_mfma_f32_16x16x32_bf16(
                        af[mi], bfr[ni], acc[mi][ni], 0, 0, 0);
        }
        __builtin_amdgcn_s_setprio(0);

        if (kk == 11) {   // nt-tile epilogue: fused running (best, second, k)
            #pragma unroll
            for (int ni = 0; ni < 4; ++ni) {
                const int c = phase * 512 + nt * BN + wn * 64 + ni * 16 + l15;
                const float cn = cnorm[c];
                #pragma unroll
                for (int mi = 0; mi < 2; ++mi) {
                    #pragma unroll
                    for (int rg = 0; rg < 4; ++rg) {
                        float d = fmaf(-2.0f, acc[mi][ni][rg], cn);
                        const int e = mi * 4 + rg;
                        float ob = runb[e];
                        runs[e] = fminf(fmaxf(d, ob), runs[e]);
                        runk[e] = (d < ob) ? c : runk[e];
                        runb[e] = fminf(d, ob);
                    }
                    acc[mi][ni] = (f32x4){0.f, 0.f, 0.f, 0.f};
                }
            }
        }
        __syncthreads();   // drains stage(t+1); ends read window of Bs[cur]
        cur ^= 1;
    }

    // cross-lane reduce within each 16-lane code-group
    #pragma unroll
    for (int e = 0; e < 8; ++e) {
        float b = runb[e], s = runs[e];
        int   k = runk[e];
        #pragma unroll
        for (int off = 1; off < 16; off <<= 1) {
            float ob = __shfl_xor(b, off, 64);
            float os = __shfl_xor(s, off, 64);
            int   ok = __shfl_xor(k, off, 64);
            float nb = fminf(b, ob);
            s = fminf(fminf(s, os), fmaxf(b, ob));
            k = (ob < b) ? ok : k;      // exact ties get flagged anyway
            b = nb;
        }
        if (l15 == 0) {
            int row = wm * 32 + (e >> 2) * 16 + l4 * 4 + (e & 3);
            mrg[row][wn][0] = b;
            mrg[row][wn][1] = s;
            mrg[row][wn][2] = __int_as_float(k);
        }
    }
    __syncthreads();

    if (tid < 64) {
        const int row = tid;
        float b0 = mrg[row][0][0], s0 = mrg[row][0][1];
        float b1 = mrg[row][1][0], s1 = mrg[row][1][1];
        int   k0 = __float_as_int(mrg[row][0][2]);
        int   k1 = __float_as_int(mrg[row][1][2]);
        float b = fminf(b0, b1);
        float s = fminf(fminf(s0, s1), fmaxf(b0, b1));
        int   k = (b1 < b0) ? k1 : k0;
        const int tok = mblk * 64 + row;
        candb[phase * NTOK + tok] = b;
        cands[phase * NTOK + tok] = s;
        candk[phase * NTOK + tok] = k;
    }
}

// ===========================================================================
// merge phases -> out_k; flag tokens with approx gap < MARGIN, init packed
// ===========================================================================
__global__ __launch_bounds__(256) void vq_merge(
    const float* __restrict__ candb, const float* __restrict__ cands,
    const int* __restrict__ candk, int* __restrict__ out_k,
    int* __restrict__ flagged, int* __restrict__ cnt,
    unsigned long long* __restrict__ packed)
{
    const int tok = blockIdx.x * 256 + threadIdx.x;
    float b = candb[tok], s = cands[tok];
    int   k = candk[tok];
    #pragma unroll
    for (int p = 1; p < NPH; ++p) {
        float pb = candb[p * NTOK + tok], ps = cands[p * NTOK + tok];
        int   pk = candk[p * NTOK + tok];
        float nb = fminf(b, pb);
        s = fminf(fminf(s, ps), fmaxf(b, pb));
        k = (pb < b) ? pk : k;
        b = nb;
    }
    out_k[tok] = k;
    if (s - b < MARGIN) {
        int i = atomicAdd(cnt, 1);
        flagged[i] = tok;
        packed[i] = 0xFFFFFFFFFFFFFFFFull;
    }
}

// ===========================================================================
// exact fp32 fallback, PARALLEL: work item = (flagged token, 1024-code chunk).
// ===========================================================================
__global__ __launch_bounds__(256) void vq_exact(
    const float* __restrict__ x, const float* __restrict__ cbT,
    const float* __restrict__ cnorm, const int* __restrict__ flagged,
    const int* __restrict__ cnt, unsigned long long* __restrict__ packed)
{
    const int tid = threadIdx.x;
    const int lane = tid & 63, wid = tid >> 6;
    const int items = (*cnt) << 2;
    __shared__ float xs[DD];
    __shared__ unsigned long long wbest[4];

    for (int w = blockIdx.x; w < items; w += gridDim.x) {
        const int ti = w >> 2;
        const int ch = w & 3;
        const int tok = flagged[ti];
        const int b = tok >> 10, hw = tok & 1023;
        __syncthreads();
        xs[tid] = x[(size_t)b * (DD * HWD) + tid * HWD + hw];
        __syncthreads();

        const int kbase = ch * 1024 + tid * 4;
        float a0 = 0.f, a1 = 0.f, a2 = 0.f, a3 = 0.f;
        #pragma unroll 8
        for (int d = 0; d < DD; ++d) {
            const float xv = xs[d];
            const float4 cv = *(const float4*)(cbT + (size_t)d * KK + kbase);
            a0 = fmaf(xv, cv.x, a0);
            a1 = fmaf(xv, cv.y, a1);
            a2 = fmaf(xv, cv.z, a2);
            a3 = fmaf(xv, cv.w, a3);
        }
        float d0 = fmaf(-2.f, a0, cnorm[kbase]);
        float d1 = fmaf(-2.f, a1, cnorm[kbase + 1]);
        float d2 = fmaf(-2.f, a2, cnorm[kbase + 2]);
        float d3 = fmaf(-2.f, a3, cnorm[kbase + 3]);
        float best = d0; int bk = kbase;
        if (d1 < best) { best = d1; bk = kbase + 1; }
        if (d2 < best) { best = d2; bk = kbase + 2; }
        if (d3 < best) { best = d3; bk = kbase + 3; }
        unsigned ub = __float_as_uint(best);
        ub = (ub & 0x80000000u) ? ~ub : (ub | 0x80000000u);   // order-preserving
        unsigned long long pk = ((unsigned long long)ub << 32) | (unsigned)bk;
        #pragma unroll
        for (int off = 1; off < 64; off <<= 1) {
            unsigned long long o = __shfl_xor(pk, off, 64);
            pk = (o < pk) ? o : pk;
        }
        if (lane == 0) wbest[wid] = pk;
        __syncthreads();
        if (tid == 0) {
            unsigned long long m = wbest[0];
            #pragma unroll
            for (int i = 1; i < 4; ++i) m = (wbest[i] < m) ? wbest[i] : m;
            atomicMin(&packed[ti], m);
        }
    }
}

__global__ __launch_bounds__(256) void vq_unpack(
    const int* __restrict__ flagged, const int* __restrict__ cnt,
    const unsigned long long* __restrict__ packed, int* __restrict__ out_k)
{
    const int i = blockIdx.x * 256 + threadIdx.x;
    if (i < *cnt) out_k[flagged[i]] = (int)(packed[i] & 0xFFFFFFFFull);
}

// ===========================================================================
// gather + transposed coalesced write
// ===========================================================================
__global__ __launch_bounds__(256) void vq_gather(const float* __restrict__ cb,
                                                 const int* __restrict__ out_k,
                                                 float* __restrict__ out) {
    const int blk = blockIdx.x;
    const int tid = threadIdx.x;
    const int b = blk >> 4;
    const int hw0 = (blk & 15) << 6;

    __shared__ int   bks[64];
    __shared__ float ts[64][65];

    if (tid < 64) bks[tid] = out_k[blk * 64 + tid];
    __syncthreads();

    const int rr = tid >> 6;
    const int j  = tid & 63;
    float* ob = out + (size_t)b * (DD * HWD) + hw0;
    #pragma unroll
    for (int c = 0; c < 4; ++c) {
        const int d0 = c << 6;
        #pragma unroll 4
        for (int it = 0; it < 16; ++it) {
            int tok = it * 4 + rr;
            ts[tok][j] = cb[bks[tok] * DD + d0 + j];
        }
        __syncthreads();
        #pragma unroll 4
        for (int it = 0; it < 16; ++it) {
            int dl = it * 4 + rr;
            ob[(d0 + dl) * HWD + j] = ts[j][dl];
        }
        __syncthreads();
    }
}

// ===========================================================================
// Small-ws fallback path (round-2 proven)
// ===========================================================================
#define TT2   64
#define KGRP2 16
#define NW2   16
__global__ __launch_bounds__(1024, 8) void vq_dist2(const float* __restrict__ x,
                                                    const float* __restrict__ cbT,
                                                    const float* __restrict__ cnorm,
                                                    float* __restrict__ cand_d,
                                                    int* __restrict__ cand_k) {
    const int blk = blockIdx.x;
    const int phase = blockIdx.y;
    const int tid = threadIdx.x;
    const int wid = tid >> 6, lane = tid & 63;
    const int b = blk >> 4;
    const int hw0 = (blk & 15) << 6;

    __shared__ alignas(16) float xs[DD * TT2];
    __shared__ float bd_s[NW2][TT2];
    __shared__ int   bk_s[NW2][TT2];

    const float* xb = x + (size_t)b * (DD * HWD) + hw0;
    #pragma unroll
    for (int it = 0; it < 16; ++it) {
        int e = it * 1024 + tid;
        int d = e >> 6, i = e & 63;
        xs[(d >> 1) * 128 + i * 2 + (d & 1)] = xb[d * HWD + i];
    }
    __syncthreads();

    const float2* xs2 = reinterpret_cast<const float2*>(xs) + lane;
    float best = 3.0e38f;
    int bestk = 0;
    const int g0 = phase * 128 + wid * 8;
    for (int j = 0; j < 8; ++j) {
        const int k0 = __builtin_amdgcn_readfirstlane((g0 + j) * KGRP2);
        const float* __restrict__ cT0 = cbT + k0;
        const float* __restrict__ cn0 = cnorm + k0;
        float acc[KGRP2];
        #pragma unroll
        for (int t = 0; t < KGRP2; ++t) acc[t] = 0.f;
        #pragma unroll 4
        for (int d2 = 0; d2 < DD / 2; ++d2) {
            float2 xv = xs2[d2 * 64];
            const float* __restrict__ cA = cT0 + (size_t)(2 * d2) * KK;
            const float* __restrict__ cB = cA + KK;
            #pragma unroll
            for (int t = 0; t < KGRP2; ++t) acc[t] = fmaf(xv.x, cA[t], acc[t]);
            #pragma unroll
            for (int t = 0; t < KGRP2; ++t) acc[t] = fmaf(xv.y, cB[t], acc[t]);
        }
        #pragma unroll
        for (int t = 0; t < KGRP2; ++t) {
            float dv = fmaf(-2.0f, acc[t], cn0[t]);
            if (dv < best) { best = dv; bestk = k0 + t; }
        }
    }
    bd_s[wid][lane] = best;
    bk_s[wid][lane] = bestk;
    __syncthreads();
    if (tid < TT2) {
        float bdv = bd_s[0][lane];
        int   bkv = bk_s[0][lane];
        #pragma unroll
        for (int w = 1; w < NW2; ++w) {
            float ddv = bd_s[w][lane];
            int   kw = bk_s[w][lane];
            if (ddv < bdv || (ddv == bdv && kw < bkv)) { bdv = ddv; bkv = kw; }
        }
        int nn = blk * TT2 + lane;
        cand_d[phase * NTOK + nn] = bdv;
        cand_k[phase * NTOK + nn] = bkv;
    }
}

__global__ __launch_bounds__(256) void vq_merge2(const float* __restrict__ cand_d,
                                                 const int* __restrict__ cand_k,
                                                 int* __restrict__ out_k) {
    const int tok = blockIdx.x * 256 + threadIdx.x;
    float d0 = cand_d[tok]; int k0 = cand_k[tok];
    float d1 = cand_d[NTOK + tok]; int k1 = cand_k[NTOK + tok];
    out_k[tok] = (d1 < d0 || (d1 == d0 && k1 < k0)) ? k1 : k0;
}

// ===========================================================================
extern "C" void kernel_launch(void* const* d_in, const int* in_sizes, int n_in,
                              void* d_out, int out_size, void* d_ws, size_t ws_size,
                              hipStream_t stream) {
    const float* x  = (const float*)d_in[0];
    const float* cb = (const float*)d_in[1];
    float* out = (float*)d_out;

    char* w = (char*)d_ws;
    float* cbT    = (float*)(w);                       // 4 MB
    float* cnorm  = (float*)(w + 4194304);             // 16 KB
    int*   out_k  = (int*)  (w + 4210688);             // 64 KB
    int*   cnt    = (int*)  (w + 4276224);             // 256 B
    int*   flagged= (int*)  (w + 4276480);             // 64 KB
    float* candb  = (float*)(w + 4342016);             // 512 KB (8 phases)
    float* cands  = (float*)(w + 4866304);             // 512 KB
    int*   candk  = (int*)  (w + 5390592);             // 512 KB
    unsigned long long* packed = (unsigned long long*)(w + 5914880); // 128 KB
    unsigned short* Ax = (unsigned short*)(w + 6045952);   // 24 MB
    unsigned short* Bc = (unsigned short*)(w + 31211776);  // 6 MB
    const size_t BIG_NEED = 37503232;

    vq_transpose<<<dim3(KK / 32, DD / 32), dim3(256), 0, stream>>>(cb, cbT);
    vq_cnorm<<<dim3(KK / 4), dim3(256), 0, stream>>>(cb, cnorm);

    if (ws_size >= BIG_NEED) {
        vq_splitx<<<dim3(256), dim3(256), 0, stream>>>(x, Ax);
        vq_splitc<<<dim3(512), dim3(256), 0, stream>>>(cb, Bc);
        vq_zero<<<dim3(1), dim3(64), 0, stream>>>(cnt);
        vq_gemm_min<<<dim3(NTOK / 64, NPH), dim3(256), 0, stream>>>(
            Ax, Bc, cnorm, candb, cands, candk);
        vq_merge<<<dim3(NTOK / 256), dim3(256), 0, stream>>>(
            candb, cands, candk, out_k, flagged, cnt, packed);
        vq_exact<<<dim3(1024), dim3(256), 0, stream>>>(
            x, cbT, cnorm, flagged, cnt, packed);
        vq_unpack<<<dim3(NTOK / 256), dim3(256), 0, stream>>>(
            flagged, cnt, packed, out_k);
    } else {
        float* cand_d = candb;
        int*   cand_k = candk;
        vq_dist2<<<dim3(NTOK / TT2, 2), dim3(1024), 0, stream>>>(
            x, cbT, cnorm, cand_d, cand_k);
        vq_merge2<<<dim3(NTOK / 256), dim3(256), 0, stream>>>(cand_d, cand_k, out_k);
    }
    vq_gather<<<dim3(NTOK / 64), dim3(256), 0, stream>>>(cb, out_k, out);
}

// Round 7
// 248.029 us; speedup vs baseline: 1.4083x; 1.4083x over previous
//
#include <hip/hip_runtime.h>
#include <math.h>

// Problem: B=16, D=256, H=32, W=32 -> N=16384 tokens; K=4096 codes.
#define DD    256
#define HWD   1024
#define NTOK  16384
#define KK    4096

typedef __attribute__((ext_vector_type(8))) short     bf16x8;
typedef __attribute__((ext_vector_type(4))) float     f32x4;
typedef __attribute__((ext_vector_type(8))) unsigned short ushort8;

// ---- bf16 helpers (RNE, bit-level) ----------------------------------------
__device__ __forceinline__ unsigned short f2bf(float f) {
    unsigned u = __float_as_uint(f);
    unsigned r = (u + 0x7FFFu + ((u >> 16) & 1u)) >> 16;
    return (unsigned short)r;
}
__device__ __forceinline__ float bf2f(unsigned short h) {
    return __uint_as_float(((unsigned)h) << 16);
}

#define GLOAD16(gaddr, laddr)                                                   \
    __builtin_amdgcn_global_load_lds(                                           \
        (const __attribute__((address_space(1))) unsigned int*)(gaddr),         \
        (__attribute__((address_space(3))) unsigned int*)(laddr), 16, 0, 0)

// ===========================================================================
// Prep A: x [16,256,1024] f32 -> Ax [16384][768] bf16 triplets (hx, lx, hx)
// ===========================================================================
__global__ __launch_bounds__(256) void vq_splitx(const float* __restrict__ x,
                                                 unsigned short* __restrict__ Ax) {
    const int blk = blockIdx.x;               // 256 blocks
    const int tid = threadIdx.x;
    const int b = blk >> 4;
    const int hw0 = (blk & 15) << 6;

    __shared__ float xls[DD * 64];            // [d][i] 64 KB

    const float* xb = x + (size_t)b * (DD * HWD) + hw0;
    #pragma unroll 8
    for (int it = 0; it < 64; ++it) {
        int e = it * 256 + tid;
        int d = e >> 6, i = e & 63;
        xls[d * 64 + i] = xb[d * HWD + i];
    }
    __syncthreads();

    const int tok_l = tid >> 2;               // 0..63
    const int part  = tid & 3;                // d-range part*64..+64
    const int n = b * HWD + hw0 + tok_l;
    unsigned short* dst = Ax + (size_t)n * 768 + part * 192;

    #pragma unroll
    for (int c8 = 0; c8 < 8; ++c8) {
        const int dbase = part * 64 + c8 * 8;
        ushort8 w0, w1, w2;
        #pragma unroll
        for (int q = 0; q < 8; ++q) {
            float v = xls[(dbase + q) * 64 + tok_l];
            unsigned short hq = f2bf(v);
            unsigned short lq = f2bf(v - bf2f(hq));
            const int i0 = 3 * q, i1 = 3 * q + 1, i2 = 3 * q + 2;
            if (i0 < 8) w0[i0] = hq; else if (i0 < 16) w1[i0 - 8] = hq; else w2[i0 - 16] = hq;
            if (i1 < 8) w0[i1] = lq; else if (i1 < 16) w1[i1 - 8] = lq; else w2[i1 - 16] = lq;
            if (i2 < 8) w0[i2] = hq; else if (i2 < 16) w1[i2 - 8] = hq; else w2[i2 - 16] = hq;
        }
        *(ushort8*)(dst + c8 * 24)      = w0;
        *(ushort8*)(dst + c8 * 24 + 8)  = w1;
        *(ushort8*)(dst + c8 * 24 + 16) = w2;
    }
}

// ===========================================================================
// Prep B: cb [4096][256] f32 -> Bc [4096][768] bf16 triplets (hc, hc, lc)
// ===========================================================================
__global__ __launch_bounds__(256) void vq_splitc(const float* __restrict__ cb,
                                                 unsigned short* __restrict__ Bc) {
    const int gid = blockIdx.x * 256 + threadIdx.x;   // 512 blocks
    const int k = gid >> 5;
    const int j = gid & 31;                           // 8 d's per thread
    const float4* cb4 = (const float4*)cb;
    float4 a = cb4[k * 64 + j * 2];
    float4 bq = cb4[k * 64 + j * 2 + 1];
    float vv[8] = {a.x, a.y, a.z, a.w, bq.x, bq.y, bq.z, bq.w};
    ushort8 w0, w1, w2;
    #pragma unroll
    for (int q = 0; q < 8; ++q) {
        unsigned short hq = f2bf(vv[q]);
        unsigned short lq = f2bf(vv[q] - bf2f(hq));
        const int i0 = 3 * q, i1 = 3 * q + 1, i2 = 3 * q + 2;
        if (i0 < 8) w0[i0] = hq; else if (i0 < 16) w1[i0 - 8] = hq; else w2[i0 - 16] = hq;
        if (i1 < 8) w0[i1] = hq; else if (i1 < 16) w1[i1 - 8] = hq; else w2[i1 - 16] = hq;
        if (i2 < 8) w0[i2] = lq; else if (i2 < 16) w1[i2 - 8] = lq; else w2[i2 - 16] = lq;
    }
    unsigned short* dst = Bc + (size_t)k * 768 + j * 24;
    *(ushort8*)(dst)      = w0;
    *(ushort8*)(dst + 8)  = w1;
    *(ushort8*)(dst + 16) = w2;
}

// ===========================================================================
// cbT [256][4096] transpose
// ===========================================================================
__global__ __launch_bounds__(256) void vq_transpose(const float* __restrict__ cb,
                                                    float* __restrict__ cbT) {
    __shared__ float t[32][33];
    const int kt = blockIdx.x * 32, dt = blockIdx.y * 32;
    const int tx = threadIdx.x & 31, ty = threadIdx.x >> 5;
    #pragma unroll
    for (int r = 0; r < 32; r += 8)
        t[ty + r][tx] = cb[(kt + ty + r) * DD + dt + tx];
    __syncthreads();
    #pragma unroll
    for (int r = 0; r < 32; r += 8)
        cbT[(size_t)(dt + ty + r) * KK + kt + tx] = t[tx][ty + r];
}

// ===========================================================================
// cnorm: exact fp32 row norms of cb
// ===========================================================================
__global__ __launch_bounds__(256) void vq_cnorm(const float* __restrict__ cb,
                                                float* __restrict__ cnorm) {
    int k = (blockIdx.x * 256 + threadIdx.x) >> 6;
    int lane = threadIdx.x & 63;
    float4 v = reinterpret_cast<const float4*>(cb)[k * 64 + lane];
    float s = v.x * v.x + v.y * v.y + v.z * v.z + v.w * v.w;
    #pragma unroll
    for (int off = 32; off > 0; off >>= 1) s += __shfl_xor(s, off, 64);
    if (lane == 0) cnorm[k] = s;
}

__global__ void vq_zero(int* cnt) { if (threadIdx.x == 0) *cnt = 0; }

// ===========================================================================
// MFMA GEMM + fused running (best, second, argmin) — round-7 structure:
//  - 128x128 tile, 4 waves (2x2), wave tile 64x64 -> 32 MFMA per K-step
//  - A AND B staged to LDS, both XOR-swizzled (pre-swizzled gload_lds source
//    + XOR'd ds_read; proven 0-conflict in round 6)
//  - double-buffered, counted vmcnt: stage(t+1) issued BEFORE compute(t);
//    s_waitcnt vmcnt(8) leaves the 8 fresh loads in flight across both raw
//    s_barriers -> no full drain in the main loop (T4)
//  - setprio(1) around MFMA cluster (T5)
// ===========================================================================
#define BN 128
#define BK 64
#define KRED 768
#define NPH 4
#define MARGIN 0.05f

__device__ __forceinline__ void stage_ab(const unsigned short* __restrict__ Ax,
                                         const unsigned short* __restrict__ Bc,
                                         unsigned short* AsF, unsigned short* BsF,
                                         int buf, int mblk, int phase, int nt, int kk,
                                         int wid, int lane) {
    const int L3  = lane >> 3;                      // dest row offset 0..7
    const int gsw = (lane & 7) ^ L3;                // pre-swizzled source chunk
    #pragma unroll
    for (int ib = 0; ib < 4; ++ib) {
        const int rb = wid * 32 + ib * 8;           // wave-uniform row base
        const int ldsoff = __builtin_amdgcn_readfirstlane(buf * 8192 + rb * 64);
        GLOAD16(Ax + (size_t)(mblk * 128 + rb + L3) * KRED + kk * 64 + gsw * 8,
                AsF + ldsoff);
        GLOAD16(Bc + (size_t)(phase * 1024 + nt * 128 + rb + L3) * KRED + kk * 64 + gsw * 8,
                BsF + ldsoff);
    }
}

__global__ __launch_bounds__(256, 2) void vq_gemm_min(
    const unsigned short* __restrict__ Ax,
    const unsigned short* __restrict__ Bc,
    const float* __restrict__ cnorm,
    float* __restrict__ candb, float* __restrict__ cands, int* __restrict__ candk)
{
    const int tid  = threadIdx.x;
    const int wid  = tid >> 6, lane = tid & 63;
    const int wm   = wid >> 1, wn = wid & 1;
    const int l15  = lane & 15, l4 = lane >> 4;     // l4 in 0..3
    const int mblk = blockIdx.x;       // 0..127 (128 tokens each)
    const int phase = blockIdx.y;      // 0..3  (1024 codes each)

    __shared__ alignas(16) unsigned short As[2 * 128 * BK];  // 32 KB dbuf
    __shared__ alignas(16) unsigned short Bs[2 * 128 * BK];  // 32 KB dbuf
    __shared__ float mrg[128][2][3];

    float runb[16], runs[16];
    int   runk[16];
    #pragma unroll
    for (int e = 0; e < 16; ++e) { runb[e] = 3.0e38f; runs[e] = 3.0e38f; runk[e] = 0; }

    f32x4 acc[4][4];
    #pragma unroll
    for (int mi = 0; mi < 4; ++mi)
        #pragma unroll
        for (int ni = 0; ni < 4; ++ni)
            acc[mi][ni] = (f32x4){0.f, 0.f, 0.f, 0.f};

    stage_ab(Ax, Bc, As, Bs, 0, mblk, phase, 0, 0, wid, lane);

    int cur = 0;
    for (int t = 0; t < 96; ++t) {                  // 8 nt-tiles x 12 K-steps
        const int nt = t / 12, kk = t - nt * 12;
        if (t < 95) {
            const int t1 = t + 1;
            const int nt1 = t1 / 12, kk1 = t1 - nt1 * 12;
            stage_ab(Ax, Bc, As, Bs, cur ^ 1, mblk, phase, nt1, kk1, wid, lane);
            asm volatile("s_waitcnt vmcnt(8)" ::: "memory");   // stage(t) landed
        } else {
            asm volatile("s_waitcnt vmcnt(0)" ::: "memory");
        }
        __builtin_amdgcn_s_barrier();

        __builtin_amdgcn_s_setprio(1);
        #pragma unroll
        for (int kh = 0; kh < 2; ++kh) {
            bf16x8 af[4], bfr[4];
            const int cxor = ((kh * 4 + l4) ^ (l15 & 7)) << 3;  // read-side XOR
            #pragma unroll
            for (int mi = 0; mi < 4; ++mi) {
                const int r = wm * 64 + mi * 16 + l15;
                af[mi] = *(const bf16x8*)&As[cur * 8192 + r * 64 + cxor];
            }
            #pragma unroll
            for (int ni = 0; ni < 4; ++ni) {
                const int c = wn * 64 + ni * 16 + l15;
                bfr[ni] = *(const bf16x8*)&Bs[cur * 8192 + c * 64 + cxor];
            }
            #pragma unroll
            for (int mi = 0; mi < 4; ++mi)
                #pragma unroll
                for (int ni = 0; ni < 4; ++ni)
                    acc[mi][ni] = __builtin_amdgcn_mfma_f32_16x16x32_bf16(
                        af[mi], bfr[ni], acc[mi][ni], 0, 0, 0);
        }
        __builtin_amdgcn_s_setprio(0);

        if (kk == 11) {   // nt-tile epilogue: fused running (best, second, k)
            #pragma unroll
            for (int ni = 0; ni < 4; ++ni) {
                const int c = phase * 1024 + nt * BN + wn * 64 + ni * 16 + l15;
                const float cn = cnorm[c];
                #pragma unroll
                for (int mi = 0; mi < 4; ++mi) {
                    #pragma unroll
                    for (int rg = 0; rg < 4; ++rg) {
                        float d = fmaf(-2.0f, acc[mi][ni][rg], cn);
                        const int e = mi * 4 + rg;
                        float ob = runb[e];
                        runs[e] = fminf(fmaxf(d, ob), runs[e]);
                        runk[e] = (d < ob) ? c : runk[e];
                        runb[e] = fminf(d, ob);
                    }
                    acc[mi][ni] = (f32x4){0.f, 0.f, 0.f, 0.f};
                }
            }
        }
        __builtin_amdgcn_s_barrier();   // end read window of buf[cur]
        cur ^= 1;
    }

    // cross-lane reduce within each 16-lane code-group
    #pragma unroll
    for (int e = 0; e < 16; ++e) {
        float b = runb[e], s = runs[e];
        int   k = runk[e];
        #pragma unroll
        for (int off = 1; off < 16; off <<= 1) {
            float ob = __shfl_xor(b, off, 64);
            float os = __shfl_xor(s, off, 64);
            int   ok = __shfl_xor(k, off, 64);
            float nb = fminf(b, ob);
            s = fminf(fminf(s, os), fmaxf(b, ob));
            k = (ob < b) ? ok : k;      // exact ties get flagged anyway
            b = nb;
        }
        if (l15 == 0) {
            int row = wm * 64 + (e >> 2) * 16 + l4 * 4 + (e & 3);
            mrg[row][wn][0] = b;
            mrg[row][wn][1] = s;
            mrg[row][wn][2] = __int_as_float(k);
        }
    }
    __syncthreads();

    if (tid < 128) {
        const int row = tid;
        float b0 = mrg[row][0][0], s0 = mrg[row][0][1];
        float b1 = mrg[row][1][0], s1 = mrg[row][1][1];
        int   k0 = __float_as_int(mrg[row][0][2]);
        int   k1 = __float_as_int(mrg[row][1][2]);
        float b = fminf(b0, b1);
        float s = fminf(fminf(s0, s1), fmaxf(b0, b1));
        int   k = (b1 < b0) ? k1 : k0;
        const int tok = mblk * 128 + row;
        candb[phase * NTOK + tok] = b;
        cands[phase * NTOK + tok] = s;
        candk[phase * NTOK + tok] = k;
    }
}

// ===========================================================================
// merge phases -> out_k; flag tokens with approx gap < MARGIN, init packed
// ===========================================================================
__global__ __launch_bounds__(256) void vq_merge(
    const float* __restrict__ candb, const float* __restrict__ cands,
    const int* __restrict__ candk, int* __restrict__ out_k,
    int* __restrict__ flagged, int* __restrict__ cnt,
    unsigned long long* __restrict__ packed)
{
    const int tok = blockIdx.x * 256 + threadIdx.x;
    float b = candb[tok], s = cands[tok];
    int   k = candk[tok];
    #pragma unroll
    for (int p = 1; p < NPH; ++p) {
        float pb = candb[p * NTOK + tok], ps = cands[p * NTOK + tok];
        int   pk = candk[p * NTOK + tok];
        float nb = fminf(b, pb);
        s = fminf(fminf(s, ps), fmaxf(b, pb));
        k = (pb < b) ? pk : k;
        b = nb;
    }
    out_k[tok] = k;
    if (s - b < MARGIN) {
        int i = atomicAdd(cnt, 1);
        flagged[i] = tok;
        packed[i] = 0xFFFFFFFFFFFFFFFFull;
    }
}

// ===========================================================================
// exact fp32 fallback, PARALLEL: work item = (flagged token, 1024-code chunk).
// ===========================================================================
__global__ __launch_bounds__(256) void vq_exact(
    const float* __restrict__ x, const float* __restrict__ cbT,
    const float* __restrict__ cnorm, const int* __restrict__ flagged,
    const int* __restrict__ cnt, unsigned long long* __restrict__ packed)
{
    const int tid = threadIdx.x;
    const int lane = tid & 63, wid = tid >> 6;
    const int items = (*cnt) << 2;
    __shared__ float xs[DD];
    __shared__ unsigned long long wbest[4];

    for (int w = blockIdx.x; w < items; w += gridDim.x) {
        const int ti = w >> 2;
        const int ch = w & 3;
        const int tok = flagged[ti];
        const int b = tok >> 10, hw = tok & 1023;
        __syncthreads();
        xs[tid] = x[(size_t)b * (DD * HWD) + tid * HWD + hw];
        __syncthreads();

        const int kbase = ch * 1024 + tid * 4;
        float a0 = 0.f, a1 = 0.f, a2 = 0.f, a3 = 0.f;
        #pragma unroll 8
        for (int d = 0; d < DD; ++d) {
            const float xv = xs[d];
            const float4 cv = *(const float4*)(cbT + (size_t)d * KK + kbase);
            a0 = fmaf(xv, cv.x, a0);
            a1 = fmaf(xv, cv.y, a1);
            a2 = fmaf(xv, cv.z, a2);
            a3 = fmaf(xv, cv.w, a3);
        }
        float d0 = fmaf(-2.f, a0, cnorm[kbase]);
        float d1 = fmaf(-2.f, a1, cnorm[kbase + 1]);
        float d2 = fmaf(-2.f, a2, cnorm[kbase + 2]);
        float d3 = fmaf(-2.f, a3, cnorm[kbase + 3]);
        float best = d0; int bk = kbase;
        if (d1 < best) { best = d1; bk = kbase + 1; }
        if (d2 < best) { best = d2; bk = kbase + 2; }
        if (d3 < best) { best = d3; bk = kbase + 3; }
        unsigned ub = __float_as_uint(best);
        ub = (ub & 0x80000000u) ? ~ub : (ub | 0x80000000u);   // order-preserving
        unsigned long long pk = ((unsigned long long)ub << 32) | (unsigned)bk;
        #pragma unroll
        for (int off = 1; off < 64; off <<= 1) {
            unsigned long long o = __shfl_xor(pk, off, 64);
            pk = (o < pk) ? o : pk;
        }
        if (lane == 0) wbest[wid] = pk;
        __syncthreads();
        if (tid == 0) {
            unsigned long long m = wbest[0];
            #pragma unroll
            for (int i = 1; i < 4; ++i) m = (wbest[i] < m) ? wbest[i] : m;
            atomicMin(&packed[ti], m);
        }
    }
}

__global__ __launch_bounds__(256) void vq_unpack(
    const int* __restrict__ flagged, const int* __restrict__ cnt,
    const unsigned long long* __restrict__ packed, int* __restrict__ out_k)
{
    const int i = blockIdx.x * 256 + threadIdx.x;
    if (i < *cnt) out_k[flagged[i]] = (int)(packed[i] & 0xFFFFFFFFull);
}

// ===========================================================================
// gather + transposed coalesced write
// ===========================================================================
__global__ __launch_bounds__(256) void vq_gather(const float* __restrict__ cb,
                                                 const int* __restrict__ out_k,
                                                 float* __restrict__ out) {
    const int blk = blockIdx.x;
    const int tid = threadIdx.x;
    const int b = blk >> 4;
    const int hw0 = (blk & 15) << 6;

    __shared__ int   bks[64];
    __shared__ float ts[64][65];

    if (tid < 64) bks[tid] = out_k[blk * 64 + tid];
    __syncthreads();

    const int rr = tid >> 6;
    const int j  = tid & 63;
    float* ob = out + (size_t)b * (DD * HWD) + hw0;
    #pragma unroll
    for (int c = 0; c < 4; ++c) {
        const int d0 = c << 6;
        #pragma unroll 4
        for (int it = 0; it < 16; ++it) {
            int tok = it * 4 + rr;
            ts[tok][j] = cb[bks[tok] * DD + d0 + j];
        }
        __syncthreads();
        #pragma unroll 4
        for (int it = 0; it < 16; ++it) {
            int dl = it * 4 + rr;
            ob[(d0 + dl) * HWD + j] = ts[j][dl];
        }
        __syncthreads();
    }
}

// ===========================================================================
// Small-ws fallback path (round-2 proven)
// ===========================================================================
#define TT2   64
#define KGRP2 16
#define NW2   16
__global__ __launch_bounds__(1024, 8) void vq_dist2(const float* __restrict__ x,
                                                    const float* __restrict__ cbT,
                                                    const float* __restrict__ cnorm,
                                                    float* __restrict__ cand_d,
                                                    int* __restrict__ cand_k) {
    const int blk = blockIdx.x;
    const int phase = blockIdx.y;
    const int tid = threadIdx.x;
    const int wid = tid >> 6, lane = tid & 63;
    const int b = blk >> 4;
    const int hw0 = (blk & 15) << 6;

    __shared__ alignas(16) float xs[DD * TT2];
    __shared__ float bd_s[NW2][TT2];
    __shared__ int   bk_s[NW2][TT2];

    const float* xb = x + (size_t)b * (DD * HWD) + hw0;
    #pragma unroll
    for (int it = 0; it < 16; ++it) {
        int e = it * 1024 + tid;
        int d = e >> 6, i = e & 63;
        xs[(d >> 1) * 128 + i * 2 + (d & 1)] = xb[d * HWD + i];
    }
    __syncthreads();

    const float2* xs2 = reinterpret_cast<const float2*>(xs) + lane;
    float best = 3.0e38f;
    int bestk = 0;
    const int g0 = phase * 128 + wid * 8;
    for (int j = 0; j < 8; ++j) {
        const int k0 = __builtin_amdgcn_readfirstlane((g0 + j) * KGRP2);
        const float* __restrict__ cT0 = cbT + k0;
        const float* __restrict__ cn0 = cnorm + k0;
        float acc[KGRP2];
        #pragma unroll
        for (int t = 0; t < KGRP2; ++t) acc[t] = 0.f;
        #pragma unroll 4
        for (int d2 = 0; d2 < DD / 2; ++d2) {
            float2 xv = xs2[d2 * 64];
            const float* __restrict__ cA = cT0 + (size_t)(2 * d2) * KK;
            const float* __restrict__ cB = cA + KK;
            #pragma unroll
            for (int t = 0; t < KGRP2; ++t) acc[t] = fmaf(xv.x, cA[t], acc[t]);
            #pragma unroll
            for (int t = 0; t < KGRP2; ++t) acc[t] = fmaf(xv.y, cB[t], acc[t]);
        }
        #pragma unroll
        for (int t = 0; t < KGRP2; ++t) {
            float dv = fmaf(-2.0f, acc[t], cn0[t]);
            if (dv < best) { best = dv; bestk = k0 + t; }
        }
    }
    bd_s[wid][lane] = best;
    bk_s[wid][lane] = bestk;
    __syncthreads();
    if (tid < TT2) {
        float bdv = bd_s[0][lane];
        int   bkv = bk_s[0][lane];
        #pragma unroll
        for (int w = 1; w < NW2; ++w) {
            float ddv = bd_s[w][lane];
            int   kw = bk_s[w][lane];
            if (ddv < bdv || (ddv == bdv && kw < bkv)) { bdv = ddv; bkv = kw; }
        }
        int nn = blk * TT2 + lane;
        cand_d[phase * NTOK + nn] = bdv;
        cand_k[phase * NTOK + nn] = bkv;
    }
}

__global__ __launch_bounds__(256) void vq_merge2(const float* __restrict__ cand_d,
                                                 const int* __restrict__ cand_k,
                                                 int* __restrict__ out_k) {
    const int tok = blockIdx.x * 256 + threadIdx.x;
    float d0 = cand_d[tok]; int k0 = cand_k[tok];
    float d1 = cand_d[NTOK + tok]; int k1 = cand_k[NTOK + tok];
    out_k[tok] = (d1 < d0 || (d1 == d0 && k1 < k0)) ? k1 : k0;
}

// ===========================================================================
extern "C" void kernel_launch(void* const* d_in, const int* in_sizes, int n_in,
                              void* d_out, int out_size, void* d_ws, size_t ws_size,
                              hipStream_t stream) {
    const float* x  = (const float*)d_in[0];
    const float* cb = (const float*)d_in[1];
    float* out = (float*)d_out;

    char* w = (char*)d_ws;
    float* cbT    = (float*)(w);                       // 4 MB
    float* cnorm  = (float*)(w + 4194304);             // 16 KB
    int*   out_k  = (int*)  (w + 4210688);             // 64 KB
    int*   cnt    = (int*)  (w + 4276224);             // 256 B
    int*   flagged= (int*)  (w + 4276480);             // 64 KB
    float* candb  = (float*)(w + 4342016);             // 512 KB (cap)
    float* cands  = (float*)(w + 4866304);             // 512 KB
    int*   candk  = (int*)  (w + 5390592);             // 512 KB
    unsigned long long* packed = (unsigned long long*)(w + 5914880); // 128 KB
    unsigned short* Ax = (unsigned short*)(w + 6045952);   // 24 MB
    unsigned short* Bc = (unsigned short*)(w + 31211776);  // 6 MB
    const size_t BIG_NEED = 37503232;

    vq_transpose<<<dim3(KK / 32, DD / 32), dim3(256), 0, stream>>>(cb, cbT);
    vq_cnorm<<<dim3(KK / 4), dim3(256), 0, stream>>>(cb, cnorm);

    if (ws_size >= BIG_NEED) {
        vq_splitx<<<dim3(256), dim3(256), 0, stream>>>(x, Ax);
        vq_splitc<<<dim3(512), dim3(256), 0, stream>>>(cb, Bc);
        vq_zero<<<dim3(1), dim3(64), 0, stream>>>(cnt);
        vq_gemm_min<<<dim3(NTOK / 128, NPH), dim3(256), 0, stream>>>(
            Ax, Bc, cnorm, candb, cands, candk);
        vq_merge<<<dim3(NTOK / 256), dim3(256), 0, stream>>>(
            candb, cands, candk, out_k, flagged, cnt, packed);
        vq_exact<<<dim3(1024), dim3(256), 0, stream>>>(
            x, cbT, cnorm, flagged, cnt, packed);
        vq_unpack<<<dim3(NTOK / 256), dim3(256), 0, stream>>>(
            flagged, cnt, packed, out_k);
    } else {
        float* cand_d = candb;
        int*   cand_k = candk;
        vq_dist2<<<dim3(NTOK / TT2, 2), dim3(1024), 0, stream>>>(
            x, cbT, cnorm, cand_d, cand_k);
        vq_merge2<<<dim3(NTOK / 256), dim3(256), 0, stream>>>(cand_d, cand_k, out_k);
    }
    vq_gather<<<dim3(NTOK / 64), dim3(256), 0, stream>>>(cb, out_k, out);
}